// Round 2
// baseline (136.780 us; speedup 1.0000x reference)
//
#include <hip/hip_runtime.h>
#include <hip/hip_bf16.h>

#define N_TOT 8192
#define DIM 256
#define HALF_B 4096
#define CHUNKS 16
#define COLS_PER_CHUNK (N_TOT / CHUNKS)      // 512
#define NT (COLS_PER_CHUNK / 16)             // 32 col-tiles per wave
#define ROWS_PER_WAVE 32
#define ROWS_PER_BLOCK 128                   // 4 waves * 32 rows
#define ROW_BLOCKS (N_TOT / ROWS_PER_BLOCK)  // 64
#define KEXP 2.8853900817779268f             // 2/T? no: (1/T=2) * log2(e)

typedef __attribute__((ext_vector_type(8))) short bfrag;   // 8 bf16 = 4 VGPRs
typedef __attribute__((ext_vector_type(4))) float facc;    // 4 f32 accum

static __device__ __forceinline__ unsigned short f2bf(float x) {
    __hip_bfloat16 h = __float2bfloat16(x);
    return __builtin_bit_cast(unsigned short, h);
}

static __device__ __forceinline__ float fast_exp2(float x) {
#if __has_builtin(__builtin_amdgcn_exp2f)
    return __builtin_amdgcn_exp2f(x);
#else
    return exp2f(x);
#endif
}

// Kernel 1: row-normalize concat(z_i, z_j) -> zn bf16 [N_TOT][DIM]
__global__ __launch_bounds__(256) void norm_kernel(const float* __restrict__ zi,
                                                   const float* __restrict__ zj,
                                                   unsigned short* __restrict__ zn) {
    int row  = blockIdx.x * 4 + (threadIdx.x >> 6);
    int lane = threadIdx.x & 63;
    const float* src = (row < HALF_B) ? (zi + (size_t)row * DIM)
                                      : (zj + (size_t)(row - HALF_B) * DIM);
    float4 v = reinterpret_cast<const float4*>(src)[lane];
    float ss = v.x * v.x + v.y * v.y + v.z * v.z + v.w * v.w;
    #pragma unroll
    for (int off = 32; off; off >>= 1) ss += __shfl_xor(ss, off);
    float inv = 1.0f / fmaxf(sqrtf(ss), 1e-8f);
    ushort4 o;
    o.x = f2bf(v.x * inv);
    o.y = f2bf(v.y * inv);
    o.z = f2bf(v.z * inv);
    o.w = f2bf(v.w * inv);
    reinterpret_cast<ushort4*>(zn + (size_t)row * DIM)[lane] = o;
}

// Kernel 2: fused zn@zn^T (bf16 MFMA) + exp row-sum partials + pos extraction.
// Grid: (ROW_BLOCKS, CHUNKS). Block: 256 thr = 4 waves, wave owns 32 rows.
// A held resident in 64 VGPRs; B-tile loads issued ahead of the exp epilogue
// so L2 latency hides under VALU work. __launch_bounds__(256,4): 128 VGPR cap,
// 4 blocks/CU (grid = 1024 = 4 * 256CU exactly).
__global__ __launch_bounds__(256, 4) void sim_kernel(const unsigned short* __restrict__ zn,
                                                     float* __restrict__ partial,
                                                     float* __restrict__ pos) {
    const int lane    = threadIdx.x & 63;
    const int wv      = threadIdx.x >> 6;
    const int rowBase = blockIdx.x * ROWS_PER_BLOCK + wv * ROWS_PER_WAVE;
    const int colStart = blockIdx.y * COLS_PER_CHUNK;
    const int lrow = lane & 15;   // A-row / B-col within 16
    const int kgrp = lane >> 4;   // 0..3
    const int koff = kgrp * 8;

    // A fragments for 2 row-tiles x 8 k-steps: keep resident all loop long.
    bfrag a[2][8];
    #pragma unroll
    for (int t = 0; t < 2; ++t)
        #pragma unroll
        for (int ks = 0; ks < 8; ++ks)
            a[t][ks] = *reinterpret_cast<const bfrag*>(
                zn + (size_t)(rowBase + t * 16 + lrow) * DIM + ks * 32 + koff);
    // Opaque-ify so the compiler cannot rematerialize (re-load) these in-loop.
    #pragma unroll
    for (int t = 0; t < 2; ++t)
        #pragma unroll
        for (int ks = 0; ks < 8; ++ks)
            asm volatile("" : "+v"(a[t][ks]));

    float rowsum[2][4] = {{0.f, 0.f, 0.f, 0.f}, {0.f, 0.f, 0.f, 0.f}};
    const int rBaseInAcc = kgrp * 4;

    facc acc0 = {0.f, 0.f, 0.f, 0.f}, acc1 = {0.f, 0.f, 0.f, 0.f};
    const unsigned short* bptr = zn + (size_t)(colStart + lrow) * DIM + koff;
    bfrag b[8];
    #pragma unroll
    for (int ks = 0; ks < 8; ++ks)
        b[ks] = *reinterpret_cast<const bfrag*>(bptr + ks * 32);
    bptr += (size_t)16 * DIM;

    #pragma unroll 1
    for (int ct = 0; ct < NT; ++ct) {
        // 1) MFMA on current tile (compiler inserts the vmcnt wait here)
        #pragma unroll
        for (int ks = 0; ks < 8; ++ks) {
            acc0 = __builtin_amdgcn_mfma_f32_16x16x32_bf16(a[0][ks], b[ks], acc0, 0, 0, 0);
            acc1 = __builtin_amdgcn_mfma_f32_16x16x32_bf16(a[1][ks], b[ks], acc1, 0, 0, 0);
        }
        // 2) issue next B-tile loads early (latency hides under epilogue)
        if (ct + 1 < NT) {
            #pragma unroll
            for (int ks = 0; ks < 8; ++ks)
                b[ks] = *reinterpret_cast<const bfrag*>(bptr + ks * 32);
            bptr += (size_t)16 * DIM;
        }
        // 3) exp epilogue for this tile (uniform branches: diag / pos / plain)
        const int colBase = colStart + ct * 16;
        #pragma unroll
        for (int t = 0; t < 2; ++t) {
            const facc ac = t ? acc1 : acc0;
            const int tRowBase = rowBase + t * 16;
            if (colBase == tRowBase) {                 // self-diagonal tile
                #pragma unroll
                for (int j = 0; j < 4; ++j) {
                    float e = fast_exp2(ac[j] * KEXP);
                    if (lrow == rBaseInAcc + j) e = 0.0f;
                    rowsum[t][j] += e;
                }
            } else if (colBase == (tRowBase ^ HALF_B)) { // positive-pair tile
                #pragma unroll
                for (int j = 0; j < 4; ++j) {
                    rowsum[t][j] += fast_exp2(ac[j] * KEXP);
                    if (lrow == rBaseInAcc + j)
                        pos[tRowBase + rBaseInAcc + j] = ac[j] * 2.0f;
                }
            } else {
                #pragma unroll
                for (int j = 0; j < 4; ++j)
                    rowsum[t][j] += fast_exp2(ac[j] * KEXP);
            }
        }
        acc0 = (facc){0.f, 0.f, 0.f, 0.f};
        acc1 = (facc){0.f, 0.f, 0.f, 0.f};
    }

    // reduce row sums across the 16 lanes holding cols 0..15
    #pragma unroll
    for (int t = 0; t < 2; ++t)
        #pragma unroll
        for (int j = 0; j < 4; ++j) {
            float v = rowsum[t][j];
            v += __shfl_xor(v, 1);
            v += __shfl_xor(v, 2);
            v += __shfl_xor(v, 4);
            v += __shfl_xor(v, 8);
            if (lrow == 0)
                partial[(size_t)blockIdx.y * N_TOT + rowBase + t * 16 + rBaseInAcc + j] = v;
        }
}

// Kernel 3: per-row lse - pos, block partial sums (deterministic)
__global__ __launch_bounds__(256) void lse_kernel(const float* __restrict__ partial,
                                                  const float* __restrict__ pos,
                                                  float* __restrict__ blockSums) {
    int r = blockIdx.x * 256 + threadIdx.x;
    float S = 0.0f;
    #pragma unroll
    for (int c = 0; c < CHUNKS; ++c) S += partial[(size_t)c * N_TOT + r];
    float v = logf(S) - pos[r];
    __shared__ float red[256];
    red[threadIdx.x] = v;
    __syncthreads();
    #pragma unroll
    for (int s = 128; s; s >>= 1) {
        if (threadIdx.x < s) red[threadIdx.x] += red[threadIdx.x + s];
        __syncthreads();
    }
    if (threadIdx.x == 0) blockSums[blockIdx.x] = red[0];
}

// Kernel 4: final reduce of 32 block sums -> loss
__global__ void final_kernel(const float* __restrict__ blockSums, float* __restrict__ out) {
    int lane = threadIdx.x;
    float v = (lane < 32) ? blockSums[lane] : 0.0f;
    #pragma unroll
    for (int off = 32; off; off >>= 1) v += __shfl_xor(v, off);
    if (lane == 0) out[0] = v / (float)N_TOT;
}

extern "C" void kernel_launch(void* const* d_in, const int* in_sizes, int n_in,
                              void* d_out, int out_size, void* d_ws, size_t ws_size,
                              hipStream_t stream) {
    const float* zi = (const float*)d_in[0];
    const float* zj = (const float*)d_in[1];
    char* ws = (char*)d_ws;

    unsigned short* zn = (unsigned short*)ws;                       // 4 MB
    float* pos        = (float*)(ws + (size_t)N_TOT * DIM * 2);     // 32 KB
    float* partial    = pos + N_TOT;                                // CHUNKS*N_TOT*4 = 512 KB
    float* blockSums  = partial + (size_t)CHUNKS * N_TOT;           // 128 B
    float* out        = (float*)d_out;

    norm_kernel<<<N_TOT / 4, 256, 0, stream>>>(zi, zj, zn);
    dim3 g2(ROW_BLOCKS, CHUNKS);
    sim_kernel<<<g2, 256, 0, stream>>>(zn, partial, pos);
    lse_kernel<<<N_TOT / 256, 256, 0, stream>>>(partial, pos, blockSums);
    final_kernel<<<1, 64, 0, stream>>>(blockSums, out);
}

// Round 3
// 53.713 us; speedup vs baseline: 2.5465x; 2.5465x over previous
//
#include <hip/hip_runtime.h>
#include <hip/hip_bf16.h>

#define N_TOT 8192
#define DIM 256
#define HALF_B 4096
#define CHUNKS 16
#define COLS_PER_CHUNK 512
#define NT 32                               // 16-col tiles per chunk
#define ROWS_PER_WAVE 32
#define ROWS_PER_BLOCK 128                  // 4 waves
#define ROW_BLOCKS 64
#define LSE_BLOCKS (N_TOT / 4)              // 2048, one wave per row
#define KEXP 2.8853900817779268f            // (1/T=2) * log2(e)

typedef __attribute__((ext_vector_type(8))) short bfrag;   // 8 bf16 = 4 VGPRs
typedef __attribute__((ext_vector_type(4))) float facc;    // 4 f32 accum

typedef __attribute__((address_space(1))) const unsigned int guint;
typedef __attribute__((address_space(3))) unsigned int luint;

static __device__ __forceinline__ void gload16(const void* g, void* l) {
    // coalesced 16B/lane global -> LDS direct (dest = wave-uniform base + lane*16)
    __builtin_amdgcn_global_load_lds((guint*)g, (luint*)l, 16, 0, 0);
}

static __device__ __forceinline__ unsigned short f2bf(float x) {
    __hip_bfloat16 h = __float2bfloat16(x);
    return __builtin_bit_cast(unsigned short, h);
}
static __device__ __forceinline__ float b2f(unsigned short u) {
    unsigned int v = ((unsigned int)u) << 16;
    return __builtin_bit_cast(float, v);
}
static __device__ __forceinline__ float fast_exp2(float x) {
#if __has_builtin(__builtin_amdgcn_exp2f)
    return __builtin_amdgcn_exp2f(x);
#else
    return exp2f(x);
#endif
}

// Kernel 1: row-normalize concat(z_i, z_j) -> zn bf16 [N_TOT][DIM]
__global__ __launch_bounds__(256) void norm_kernel(const float* __restrict__ zi,
                                                   const float* __restrict__ zj,
                                                   unsigned short* __restrict__ zn) {
    int row  = blockIdx.x * 4 + (threadIdx.x >> 6);
    int lane = threadIdx.x & 63;
    const float* src = (row < HALF_B) ? (zi + (size_t)row * DIM)
                                      : (zj + (size_t)(row - HALF_B) * DIM);
    float4 v = reinterpret_cast<const float4*>(src)[lane];
    float ss = v.x * v.x + v.y * v.y + v.z * v.z + v.w * v.w;
    #pragma unroll
    for (int off = 32; off; off >>= 1) ss += __shfl_xor(ss, off);
    float inv = 1.0f / fmaxf(sqrtf(ss), 1e-8f);
    ushort4 o;
    o.x = f2bf(v.x * inv);
    o.y = f2bf(v.y * inv);
    o.z = f2bf(v.z * inv);
    o.w = f2bf(v.w * inv);
    reinterpret_cast<ushort4*>(zn + (size_t)row * DIM)[lane] = o;
}

// Kernel 2: fused zn@zn^T (bf16 MFMA) + exp row-sum partials.
// B tiles (16 cols x 256 k = 8KB) staged via global_load_lds (coalesced),
// XOR-swizzled (pre-swizzled global source + swizzled ds_read -> conflict-free).
// A (32 rows/wave) resident in registers. Double-buffer, 2 barriers/tile (safe).
__global__ __launch_bounds__(256, 4) void sim_kernel(const unsigned short* __restrict__ zn,
                                                     float* __restrict__ partial) {
    __shared__ __align__(16) unsigned short smem[2 * 4096];   // 2 bufs x 8KB
    const int lane = threadIdx.x & 63;
    const int wv   = threadIdx.x >> 6;
    const int rowBase  = blockIdx.x * ROWS_PER_BLOCK + wv * ROWS_PER_WAVE;
    const int colStart = blockIdx.y * COLS_PER_CHUNK;
    const int lrow = lane & 15;    // A-row / B-col within 16
    const int kq   = lane >> 4;    // k-group 0..3
    const int swzE = (lrow & 7) << 3;   // XOR swizzle in elements (16B granules)

    // A fragments: 2 tiles x 8 ksteps, kept live across the whole loop
    bfrag a[2][8];
    #pragma unroll
    for (int t = 0; t < 2; ++t)
        #pragma unroll
        for (int ks = 0; ks < 8; ++ks)
            a[t][ks] = *reinterpret_cast<const bfrag*>(
                zn + (size_t)(rowBase + t * 16 + lrow) * DIM + ks * 32 + kq * 8);

    // staging address precompute: thread covers two 16B chunks of the 8KB tile
    const int t0 = wv * 64 + lane;          // 16B-chunk id 0..255
    const int t1 = t0 + 256;                // 16B-chunk id 256..511
    const int r0 = t0 >> 5, c0 = t0 & 31;   // row (of 16), chunk-in-row (of 32)
    const int r1 = t1 >> 5, c1 = t1 & 31;
    // pre-swizzled SOURCE (inverse == same involution), elems:
    const int srcOff0 = r0 * DIM + ((c0 * 8) ^ ((r0 & 7) << 3));
    const int srcOff1 = r1 * DIM + ((c1 * 8) ^ ((r1 & 7) << 3));
    const int ldsW0 = (wv * 64) * 8;        // wave-uniform LDS dest (ushort idx)
    const int ldsW1 = (256 + wv * 64) * 8;
    const unsigned short* znT = zn + (size_t)colStart * DIM;

    float rowsum[2][4] = {{0.f, 0.f, 0.f, 0.f}, {0.f, 0.f, 0.f, 0.f}};

#define STAGE(buf, ct) do {                                                  \
        const unsigned short* gsb = znT + (size_t)(ct) * (16 * DIM);         \
        gload16(gsb + srcOff0, smem + (buf) * 4096 + ldsW0);                 \
        gload16(gsb + srcOff1, smem + (buf) * 4096 + ldsW1);                 \
    } while (0)

    STAGE(0, 0);

    #pragma unroll 1
    for (int ct = 0; ct < NT; ++ct) {
        const int cur = ct & 1;
        __syncthreads();                      // all waves done reading buf[cur^1]
        if (ct + 1 < NT) STAGE(cur ^ 1, ct + 1);
        __syncthreads();                      // vmcnt drained: buf[cur] fully staged

        const unsigned short* base = smem + cur * 4096 + lrow * DIM;
        facc acc0 = {0.f, 0.f, 0.f, 0.f}, acc1 = {0.f, 0.f, 0.f, 0.f};
        bfrag bb[4];
        #pragma unroll
        for (int ks = 0; ks < 4; ++ks)
            bb[ks] = *reinterpret_cast<const bfrag*>(base + ((ks * 32 + kq * 8) ^ swzE));
        #pragma unroll
        for (int ks = 0; ks < 4; ++ks) {
            acc0 = __builtin_amdgcn_mfma_f32_16x16x32_bf16(a[0][ks], bb[ks], acc0, 0, 0, 0);
            acc1 = __builtin_amdgcn_mfma_f32_16x16x32_bf16(a[1][ks], bb[ks], acc1, 0, 0, 0);
        }
        #pragma unroll
        for (int ks = 4; ks < 8; ++ks)
            bb[ks - 4] = *reinterpret_cast<const bfrag*>(base + ((ks * 32 + kq * 8) ^ swzE));
        #pragma unroll
        for (int ks = 4; ks < 8; ++ks) {
            acc0 = __builtin_amdgcn_mfma_f32_16x16x32_bf16(a[0][ks], bb[ks - 4], acc0, 0, 0, 0);
            acc1 = __builtin_amdgcn_mfma_f32_16x16x32_bf16(a[1][ks], bb[ks - 4], acc1, 0, 0, 0);
        }

        // epilogue: exp row-sums; mask self-diagonal
        const int colBase = colStart + ct * 16;
        #pragma unroll
        for (int t = 0; t < 2; ++t) {
            const facc ac = t ? acc1 : acc0;
            const int tRowBase = rowBase + t * 16;
            if (colBase == tRowBase) {
                #pragma unroll
                for (int j = 0; j < 4; ++j) {
                    float e = fast_exp2(ac[j] * KEXP);
                    if (lrow == kq * 4 + j) e = 0.0f;    // exclude self
                    rowsum[t][j] += e;
                }
            } else {
                #pragma unroll
                for (int j = 0; j < 4; ++j)
                    rowsum[t][j] += fast_exp2(ac[j] * KEXP);
            }
        }
    }
#undef STAGE

    // reduce row sums across the 16 lanes holding cols 0..15
    #pragma unroll
    for (int t = 0; t < 2; ++t)
        #pragma unroll
        for (int j = 0; j < 4; ++j) {
            float v = rowsum[t][j];
            v += __shfl_xor(v, 1);
            v += __shfl_xor(v, 2);
            v += __shfl_xor(v, 4);
            v += __shfl_xor(v, 8);
            if (lrow == 0)
                partial[(size_t)blockIdx.y * N_TOT + rowBase + t * 16 + kq * 4 + j] = v;
        }
}

// Kernel 3: one wave per row: pos = 2*dot(zn[r], zn[r^B]) computed directly;
// lse = log(sum of 16 chunk partials); block emits sum of 4 rows.
__global__ __launch_bounds__(256) void lse_kernel(const unsigned short* __restrict__ zn,
                                                  const float* __restrict__ partial,
                                                  float* __restrict__ blockSums) {
    const int lane = threadIdx.x & 63;
    const int wv   = threadIdx.x >> 6;
    const int r    = blockIdx.x * 4 + wv;
    const int rp   = r ^ HALF_B;
    ushort4 va = reinterpret_cast<const ushort4*>(zn + (size_t)r  * DIM)[lane];
    ushort4 vb = reinterpret_cast<const ushort4*>(zn + (size_t)rp * DIM)[lane];
    float d = b2f(va.x) * b2f(vb.x) + b2f(va.y) * b2f(vb.y) +
              b2f(va.z) * b2f(vb.z) + b2f(va.w) * b2f(vb.w);
    #pragma unroll
    for (int off = 32; off; off >>= 1) d += __shfl_xor(d, off);
    float S = (lane < CHUNKS) ? partial[(size_t)lane * N_TOT + r] : 0.0f;
    #pragma unroll
    for (int off = 8; off; off >>= 1) S += __shfl_xor(S, off);
    __shared__ float red[4];
    if (lane == 0) red[wv] = logf(S) - d * 2.0f;
    __syncthreads();
    if (threadIdx.x == 0)
        blockSums[blockIdx.x] = red[0] + red[1] + red[2] + red[3];
}

// Kernel 4: reduce 2048 block sums -> loss
__global__ __launch_bounds__(256) void final_kernel(const float* __restrict__ bs,
                                                    float* __restrict__ out) {
    int t = threadIdx.x;
    float v = 0.0f;
    #pragma unroll
    for (int i = 0; i < LSE_BLOCKS / 256; ++i) v += bs[t + i * 256];
    #pragma unroll
    for (int off = 32; off; off >>= 1) v += __shfl_xor(v, off);
    __shared__ float red[4];
    if ((t & 63) == 0) red[t >> 6] = v;
    __syncthreads();
    if (t == 0) out[0] = (red[0] + red[1] + red[2] + red[3]) / (float)N_TOT;
}

extern "C" void kernel_launch(void* const* d_in, const int* in_sizes, int n_in,
                              void* d_out, int out_size, void* d_ws, size_t ws_size,
                              hipStream_t stream) {
    const float* zi = (const float*)d_in[0];
    const float* zj = (const float*)d_in[1];
    char* ws = (char*)d_ws;

    unsigned short* zn = (unsigned short*)ws;                       // 4 MB
    float* partial    = (float*)(ws + (size_t)N_TOT * DIM * 2);     // 512 KB
    float* blockSums  = partial + (size_t)CHUNKS * N_TOT;           // 8 KB
    float* out        = (float*)d_out;

    norm_kernel<<<N_TOT / 4, 256, 0, stream>>>(zi, zj, zn);
    dim3 g2(ROW_BLOCKS, CHUNKS);
    sim_kernel<<<g2, 256, 0, stream>>>(zn, partial);
    lse_kernel<<<LSE_BLOCKS, 256, 0, stream>>>(zn, partial, blockSums);
    final_kernel<<<1, 256, 0, stream>>>(blockSums, out);
}

// Round 4
// 50.969 us; speedup vs baseline: 2.6836x; 1.0538x over previous
//
#include <hip/hip_runtime.h>
#include <hip/hip_bf16.h>

#define N_TOT 8192
#define DIM 256
#define HALF_B 4096
#define CHUNKS 16
#define COLS_PER_CHUNK 512
#define TILE_COLS 64
#define NTILES (COLS_PER_CHUNK / TILE_COLS)   // 8 staged tiles per chunk
#define ROWS_PER_WAVE 64
#define ROWS_PER_BLOCK 256                    // 4 waves * 64 rows
#define ROW_BLOCKS (N_TOT / ROWS_PER_BLOCK)   // 32
#define LSE_BLOCKS (N_TOT / 4)                // 2048
#define KEXP 2.8853900817779268f              // (1/T=2) * log2(e)
#define TILE_USHORTS (TILE_COLS * DIM)        // 16384 ushorts = 32KB

typedef __attribute__((ext_vector_type(8))) short bfrag;   // 8 bf16 = 4 VGPRs
typedef __attribute__((ext_vector_type(4))) float facc;    // 4 f32 accum

typedef __attribute__((address_space(1))) const unsigned int guint;
typedef __attribute__((address_space(3))) unsigned int luint;

static __device__ __forceinline__ void gload16(const void* g, void* l) {
    __builtin_amdgcn_global_load_lds((guint*)g, (luint*)l, 16, 0, 0);
}
static __device__ __forceinline__ unsigned short f2bf(float x) {
    __hip_bfloat16 h = __float2bfloat16(x);
    return __builtin_bit_cast(unsigned short, h);
}
static __device__ __forceinline__ float b2f(unsigned short u) {
    unsigned int v = ((unsigned int)u) << 16;
    return __builtin_bit_cast(float, v);
}
static __device__ __forceinline__ float fast_exp2(float x) {
#if __has_builtin(__builtin_amdgcn_exp2f)
    return __builtin_amdgcn_exp2f(x);
#else
    return exp2f(x);
#endif
}

// Kernel 1: row-normalize concat(z_i, z_j) -> zn bf16 [N_TOT][DIM]
__global__ __launch_bounds__(256) void norm_kernel(const float* __restrict__ zi,
                                                   const float* __restrict__ zj,
                                                   unsigned short* __restrict__ zn) {
    int row  = blockIdx.x * 4 + (threadIdx.x >> 6);
    int lane = threadIdx.x & 63;
    const float* src = (row < HALF_B) ? (zi + (size_t)row * DIM)
                                      : (zj + (size_t)(row - HALF_B) * DIM);
    float4 v = reinterpret_cast<const float4*>(src)[lane];
    float ss = v.x * v.x + v.y * v.y + v.z * v.z + v.w * v.w;
    #pragma unroll
    for (int off = 32; off; off >>= 1) ss += __shfl_xor(ss, off);
    float inv = 1.0f / fmaxf(sqrtf(ss), 1e-8f);
    ushort4 o;
    o.x = f2bf(v.x * inv);
    o.y = f2bf(v.y * inv);
    o.z = f2bf(v.z * inv);
    o.w = f2bf(v.w * inv);
    reinterpret_cast<ushort4*>(zn + (size_t)row * DIM)[lane] = o;
}

// Kernel 2: fused zn@zn^T (bf16 MFMA) + exp row-sum partials.
// 64 rows/wave resident in regs (4 row-tiles x 8 ksteps = 128 VGPR).
// B staged in 64-col x 256-k tiles (32KB), double-buffered, XOR-swizzled,
// single barrier per tile: STAGE(next) issued before compute(cur), drain at
// the iteration-ending __syncthreads (vmcnt(0) folds into the barrier).
__global__ __launch_bounds__(256, 2) void sim_kernel(const unsigned short* __restrict__ zn,
                                                     float* __restrict__ partial) {
    __shared__ __align__(16) unsigned short smem[2 * TILE_USHORTS];   // 64KB
    const int lane = threadIdx.x & 63;
    const int wv   = threadIdx.x >> 6;
    const int rowBase  = blockIdx.x * ROWS_PER_BLOCK + wv * ROWS_PER_WAVE;
    const int colStart = blockIdx.y * COLS_PER_CHUNK;
    const int lrow = lane & 15;         // A-row / B-col within 16
    const int kq   = lane >> 4;         // k-group 0..3
    const int swzE = (lrow & 7) << 3;   // XOR swizzle (elements)

    // A fragments: 4 row-tiles x 8 ksteps, kept live across the whole loop
    bfrag a[4][8];
    #pragma unroll
    for (int t = 0; t < 4; ++t)
        #pragma unroll
        for (int ks = 0; ks < 8; ++ks)
            a[t][ks] = *reinterpret_cast<const bfrag*>(
                zn + (size_t)(rowBase + t * 16 + lrow) * DIM + ks * 32 + kq * 8);
    #pragma unroll
    for (int t = 0; t < 4; ++t)
        #pragma unroll
        for (int ks = 0; ks < 8; ++ks)
            asm volatile("" : "+v"(a[t][ks]));

    // staging: tile = 64 rows x 256 k = 2048 16B-chunks; wave wv stages
    // segments s = wv*8+i (64 chunks = 1KB each, lane-linear LDS dest).
    int srcOff[8];
    #pragma unroll
    for (int i = 0; i < 8; ++i) {
        int c  = (wv * 8 + i) * 64 + lane;   // chunk id 0..2047
        int r  = c >> 5;                     // tile row 0..63
        int cc = c & 31;                     // 16B-chunk within row
        srcOff[i] = r * DIM + ((cc * 8) ^ ((r & 7) << 3));  // pre-swizzled src
    }
    const unsigned short* znT = zn + (size_t)colStart * DIM;

#define STAGE(buf, ct) do {                                                   \
        const unsigned short* gsb = znT + (size_t)(ct) * (TILE_COLS * DIM);   \
        _Pragma("unroll")                                                     \
        for (int i = 0; i < 8; ++i)                                           \
            gload16(gsb + srcOff[i],                                          \
                    smem + (buf) * TILE_USHORTS + (wv * 8 + i) * 512);        \
    } while (0)

    float rowsum[4][4];
    #pragma unroll
    for (int t = 0; t < 4; ++t)
        #pragma unroll
        for (int j = 0; j < 4; ++j) rowsum[t][j] = 0.0f;

    STAGE(0, 0);
    __syncthreads();                      // drain tile 0

    #pragma unroll 1
    for (int tile = 0; tile < NTILES; ++tile) {
        const int cur = tile & 1;
        if (tile + 1 < NTILES) STAGE(cur ^ 1, tile + 1);   // hides under MFMA

        #pragma unroll
        for (int cs = 0; cs < 4; ++cs) {                   // 16-col subtiles
            const unsigned short* base =
                smem + cur * TILE_USHORTS + (cs * 16 + lrow) * DIM;
            bfrag bb[8];
            #pragma unroll
            for (int ks = 0; ks < 8; ++ks)
                bb[ks] = *reinterpret_cast<const bfrag*>(
                    base + ((ks * 32 + kq * 8) ^ swzE));
            facc acc[4];
            #pragma unroll
            for (int t = 0; t < 4; ++t) acc[t] = (facc){0.f, 0.f, 0.f, 0.f};
            #pragma unroll
            for (int ks = 0; ks < 8; ++ks)
                #pragma unroll
                for (int t = 0; t < 4; ++t)
                    acc[t] = __builtin_amdgcn_mfma_f32_16x16x32_bf16(
                        a[t][ks], bb[ks], acc[t], 0, 0, 0);

            const int colBase = colStart + tile * TILE_COLS + cs * 16;
            #pragma unroll
            for (int t = 0; t < 4; ++t) {
                const int tRowBase = rowBase + t * 16;
                if (colBase == tRowBase) {                 // self-diagonal tile
                    #pragma unroll
                    for (int j = 0; j < 4; ++j) {
                        float e = fast_exp2(acc[t][j] * KEXP);
                        if (lrow == kq * 4 + j) e = 0.0f;  // exclude self
                        rowsum[t][j] += e;
                    }
                } else {
                    #pragma unroll
                    for (int j = 0; j < 4; ++j)
                        rowsum[t][j] += fast_exp2(acc[t][j] * KEXP);
                }
            }
        }
        __syncthreads();   // vmcnt(0)+barrier: next tile staged, reads done
    }
#undef STAGE

    // reduce row sums across the 16 lanes holding cols 0..15
    #pragma unroll
    for (int t = 0; t < 4; ++t)
        #pragma unroll
        for (int j = 0; j < 4; ++j) {
            float v = rowsum[t][j];
            v += __shfl_xor(v, 1);
            v += __shfl_xor(v, 2);
            v += __shfl_xor(v, 4);
            v += __shfl_xor(v, 8);
            if (lrow == 0)
                partial[(size_t)blockIdx.y * N_TOT + rowBase + t * 16 + kq * 4 + j] = v;
        }
}

// Kernel 3: one wave per row: pos = 2*dot(zn[r], zn[r^B]); lse = log(sum partials)
__global__ __launch_bounds__(256) void lse_kernel(const unsigned short* __restrict__ zn,
                                                  const float* __restrict__ partial,
                                                  float* __restrict__ blockSums) {
    const int lane = threadIdx.x & 63;
    const int wv   = threadIdx.x >> 6;
    const int r    = blockIdx.x * 4 + wv;
    const int rp   = r ^ HALF_B;
    ushort4 va = reinterpret_cast<const ushort4*>(zn + (size_t)r  * DIM)[lane];
    ushort4 vb = reinterpret_cast<const ushort4*>(zn + (size_t)rp * DIM)[lane];
    float d = b2f(va.x) * b2f(vb.x) + b2f(va.y) * b2f(vb.y) +
              b2f(va.z) * b2f(vb.z) + b2f(va.w) * b2f(vb.w);
    #pragma unroll
    for (int off = 32; off; off >>= 1) d += __shfl_xor(d, off);
    float S = (lane < CHUNKS) ? partial[(size_t)lane * N_TOT + r] : 0.0f;
    #pragma unroll
    for (int off = 8; off; off >>= 1) S += __shfl_xor(S, off);
    __shared__ float red[4];
    if (lane == 0) red[wv] = logf(S) - d * 2.0f;
    __syncthreads();
    if (threadIdx.x == 0)
        blockSums[blockIdx.x] = red[0] + red[1] + red[2] + red[3];
}

// Kernel 4: reduce 2048 block sums -> loss
__global__ __launch_bounds__(256) void final_kernel(const float* __restrict__ bs,
                                                    float* __restrict__ out) {
    int t = threadIdx.x;
    float v = 0.0f;
    #pragma unroll
    for (int i = 0; i < LSE_BLOCKS / 256; ++i) v += bs[t + i * 256];
    #pragma unroll
    for (int off = 32; off; off >>= 1) v += __shfl_xor(v, off);
    __shared__ float red[4];
    if ((t & 63) == 0) red[t >> 6] = v;
    __syncthreads();
    if (t == 0) out[0] = (red[0] + red[1] + red[2] + red[3]) / (float)N_TOT;
}

extern "C" void kernel_launch(void* const* d_in, const int* in_sizes, int n_in,
                              void* d_out, int out_size, void* d_ws, size_t ws_size,
                              hipStream_t stream) {
    const float* zi = (const float*)d_in[0];
    const float* zj = (const float*)d_in[1];
    char* ws = (char*)d_ws;

    unsigned short* zn = (unsigned short*)ws;                       // 4 MB
    float* partial    = (float*)(ws + (size_t)N_TOT * DIM * 2);     // 512 KB
    float* blockSums  = partial + (size_t)CHUNKS * N_TOT;           // 8 KB
    float* out        = (float*)d_out;

    norm_kernel<<<N_TOT / 4, 256, 0, stream>>>(zi, zj, zn);
    dim3 g2(ROW_BLOCKS, CHUNKS);
    sim_kernel<<<g2, 256, 0, stream>>>(zn, partial);
    lse_kernel<<<LSE_BLOCKS, 256, 0, stream>>>(zn, partial, blockSums);
    final_kernel<<<1, 256, 0, stream>>>(blockSums, out);
}